// Round 11
// baseline (3635.749 us; speedup 1.0000x reference)
//
#include <hip/hip_runtime.h>
#include <cmath>

typedef _Float16 f16x8 __attribute__((ext_vector_type(8)));
typedef float f32x4 __attribute__((ext_vector_type(4)));

#define MFMA16 __builtin_amdgcn_mfma_f32_16x16x32_f16
#define HS 264   // padded f32 row stride

__device__ __forceinline__ float sigm(float x) { return 1.0f / (1.0f + expf(-x)); }
__device__ __forceinline__ unsigned short f16b(float x) {
    _Float16 h = (_Float16)x; return __builtin_bit_cast(unsigned short, h);
}

// ---------------- weight prep: pack into per-lane MFMA B-fragment layout ----------
// frag element j of lane l = W[k0 + (l>>4)*8 + j][nt*16 + (l&15)]  (k0 = kt*32)
__global__ __launch_bounds__(256) void conv_gru(
    const float* __restrict__ gate_k, const float* __restrict__ cand_k,
    f16x8* __restrict__ gB, f16x8* __restrict__ cB, int* __restrict__ ctr)
{
    if (blockIdx.x == 0 && threadIdx.x < 33) ctr[threadIdx.x] = 0;  // 32 chunk flags + gctr
    int i = blockIdx.x * 256 + threadIdx.x;
    if (i < 8*16*32*64) {          // gate: [e2][kt 16][nt 32][l 64]
        int l = i & 63, nt = (i >> 6) & 31, kt = (i >> 11) & 15, e2 = i >> 15;
        int k0 = kt*32 + ((l >> 4) << 3);
        int n  = (nt << 4) + (l & 15);
        const float* src = gate_k + ((size_t)(e2*512 + k0)) * 512 + n;
        f16x8 v;
        #pragma unroll
        for (int j = 0; j < 8; ++j) v[j] = (_Float16)__builtin_nontemporal_load(&src[(size_t)j * 512]);
        __builtin_nontemporal_store(v, &gB[i]);
    }
    if (i < 8*16*16*64) {          // cand: [e2][kt 16][nt 16][l 64]
        int l = i & 63, nt = (i >> 6) & 15, kt = (i >> 10) & 15, e2 = i >> 14;
        int k0 = kt*32 + ((l >> 4) << 3);
        int n  = (nt << 4) + (l & 15);
        const float* src = cand_k + ((size_t)(e2*512 + k0)) * 256 + n;
        f16x8 v;
        #pragma unroll
        for (int j = 0; j < 8; ++j) v[j] = (_Float16)__builtin_nontemporal_load(&src[(size_t)j * 256]);
        __builtin_nontemporal_store(v, &cB[i]);
    }
}

__global__ __launch_bounds__(256) void conv_wprod(const float* __restrict__ w1,
                                                  f16x8* __restrict__ wB)
{
    int i = blockIdx.x * 256 + threadIdx.x;   // [kt 32][nt 64][l 64]
    int l = i & 63, nt = (i >> 6) & 63, kt = i >> 12;
    int k0 = kt*32 + ((l >> 4) << 3);
    int n  = (nt << 4) + (l & 15);
    const float* src = w1 + (size_t)(2049 + k0) * 1024 + n;
    f16x8 v;
    #pragma unroll
    for (int j = 0; j < 8; ++j) v[j] = (_Float16)__builtin_nontemporal_load(&src[(size_t)j * 1024]);
    __builtin_nontemporal_store(v, &wB[i]);
}

// ---------------- GRU encode: 256 blocks (1/CU), strict XCD-affine chunks ---------
// f16 LDS segs [16 rows][256 cols], u16 idx = row*256 + (col ^ ((row&7)<<3))
__device__ __forceinline__ void gate_phase(const unsigned short* SX, const unsigned short* SH,
    unsigned short* Hdst, float* gzs, const float* st, const float* gbL,
    const f16x8* gBL, int w, int l)
{
    int arow = l & 15, sel = arow & 7, ak = l >> 4;
    const f16x8* px = (const f16x8*)SX + arow * 32;
    const f16x8* ph = (const f16x8*)SH + arow * 32;
    f32x4 acc0 = {0.f,0.f,0.f,0.f}, acc1 = {0.f,0.f,0.f,0.f};
    const f16x8* bp = gBL + l;
    int nt0 = 2*w;
    #pragma unroll
    for (int h = 0; h < 2; ++h) {
        const f16x8* ap = h ? ph : px;
        #pragma unroll
        for (int g = 0; g < 2; ++g) {
            int kb = h*8 + g*4, la = g*4;
            // 8 independent b-frag loads issued together (deep vmcnt pipeline)
            f16x8 b00 = bp[(size_t)((kb+0)*32 + nt0) * 64];
            f16x8 b01 = bp[(size_t)((kb+0)*32 + nt0 + 1) * 64];
            f16x8 b10 = bp[(size_t)((kb+1)*32 + nt0) * 64];
            f16x8 b11 = bp[(size_t)((kb+1)*32 + nt0 + 1) * 64];
            f16x8 b20 = bp[(size_t)((kb+2)*32 + nt0) * 64];
            f16x8 b21 = bp[(size_t)((kb+2)*32 + nt0 + 1) * 64];
            f16x8 b30 = bp[(size_t)((kb+3)*32 + nt0) * 64];
            f16x8 b31 = bp[(size_t)((kb+3)*32 + nt0 + 1) * 64];
            f16x8 a0 = ap[((la+0)*4 + ak) ^ sel];
            f16x8 a1 = ap[((la+1)*4 + ak) ^ sel];
            f16x8 a2 = ap[((la+2)*4 + ak) ^ sel];
            f16x8 a3 = ap[((la+3)*4 + ak) ^ sel];
            acc0 = MFMA16(a0, b00, acc0, 0, 0, 0); acc1 = MFMA16(a0, b01, acc1, 0, 0, 0);
            acc0 = MFMA16(a1, b10, acc0, 0, 0, 0); acc1 = MFMA16(a1, b11, acc1, 0, 0, 0);
            acc0 = MFMA16(a2, b20, acc0, 0, 0, 0); acc1 = MFMA16(a2, b21, acc1, 0, 0, 0);
            acc0 = MFMA16(a3, b30, acc0, 0, 0, 0); acc1 = MFMA16(a3, b31, acc1, 0, 0, 0);
        }
    }
    int r0 = (l >> 4) * 4;
    #pragma unroll
    for (int h = 0; h < 2; ++h) {
        f32x4 acc = h ? acc1 : acc0;
        int col = (nt0 + h) * 16 + (l & 15);
        if (col < 256) {            // r-gate (wave-uniform branch)
            #pragma unroll
            for (int j = 0; j < 4; ++j) {
                int row = r0 + j;
                float rv = sigm(acc[j] + gbL[col]);
                float rh = rv * st[row*HS + col];
                Hdst[row*256 + (col ^ ((row & 7) << 3))] = f16b(rh);
            }
        } else {                    // z-gate
            int zc = col - 256;
            #pragma unroll
            for (int j = 0; j < 4; ++j) {
                int row = r0 + j;
                gzs[row*HS + zc] = sigm(acc[j] + gbL[col]);
            }
        }
    }
}

template<int LAYER>
__device__ __forceinline__ void cand_phase(const unsigned short* SX, const unsigned short* SH,
    unsigned short* Xdst, unsigned short* Hstage,
    float* st, const float* oth, const float* gzs, const float* cbL, const f16x8* cBL,
    const float* __restrict__ emb, const int* tok_s, const int* len_s, int t,
    int w, int l)
{
    int arow = l & 15, sel = arow & 7, ak = l >> 4;
    const f16x8* px = (const f16x8*)SX + arow * 32;
    const f16x8* ph = (const f16x8*)SH + arow * 32;
    f32x4 acc = {0.f,0.f,0.f,0.f};
    const f16x8* bp = cBL + l;
    #pragma unroll
    for (int h = 0; h < 2; ++h) {
        const f16x8* ap = h ? ph : px;
        #pragma unroll
        for (int g = 0; g < 2; ++g) {
            int kb = h*8 + g*4, la = g*4;
            f16x8 b0 = bp[(size_t)((kb+0)*16 + w) * 64];
            f16x8 b1 = bp[(size_t)((kb+1)*16 + w) * 64];
            f16x8 b2 = bp[(size_t)((kb+2)*16 + w) * 64];
            f16x8 b3 = bp[(size_t)((kb+3)*16 + w) * 64];
            f16x8 a0 = ap[((la+0)*4 + ak) ^ sel];
            f16x8 a1 = ap[((la+1)*4 + ak) ^ sel];
            f16x8 a2 = ap[((la+2)*4 + ak) ^ sel];
            f16x8 a3 = ap[((la+3)*4 + ak) ^ sel];
            acc = MFMA16(a0, b0, acc, 0, 0, 0);
            acc = MFMA16(a1, b1, acc, 0, 0, 0);
            acc = MFMA16(a2, b2, acc, 0, 0, 0);
            acc = MFMA16(a3, b3, acc, 0, 0, 0);
        }
    }
    int r0 = (l >> 4) * 4;
    int col = w*16 + (l & 15);
    #pragma unroll
    for (int j = 0; j < 4; ++j) {
        int row = r0 + j;
        float cv = tanhf(acc[j] + cbL[col]);
        float z  = gzs[row*HS + col];
        float hv = st[row*HS + col];
        float hn = fmaf(z, hv - cv, cv);
        if (t < len_s[row]) st[row*HS + col] = hn;
        int sw = col ^ ((row & 7) << 3);
        if (LAYER == 1) {
            Xdst[row*256 + sw]   = f16b(hn);                         // layer-2 x (unmasked)
            Hstage[row*256 + sw] = f16b(oth[row*HS + col]);          // stage h2
        } else {
            Xdst[row*256 + sw]   = f16b(emb[(size_t)tok_s[row]*256 + col]); // x(t+1)
            Hstage[row*256 + sw] = f16b(oth[row*HS + col]);          // stage h1
        }
    }
}

__global__ __launch_bounds__(1024, 4) void gru_encode(
    const int* __restrict__ iq, const int* __restrict__ ir,
    const int* __restrict__ ql, const int* __restrict__ rl,
    const float* __restrict__ emb,
    const float* __restrict__ gate_b, const float* __restrict__ cand_b,
    const f16x8* __restrict__ gB, const f16x8* __restrict__ cB,
    int* __restrict__ ctr,
    float* __restrict__ Qo, float* __restrict__ Ro)
{
    int tid = threadIdx.x;
    int w = tid >> 6, l = tid & 63;

    // STRICT XCD-affine claim: this XCD's 4 chunks only. chunk = xcd*4 + c
    // (encoder = chunk>>3, so XCD pair {2e,2e+1} owns encoder e). Losers wait
    // (bounded) for rightful owners, then steal leftovers (correctness net).
    __shared__ int sh_ec;
    if (tid == 0) {
        unsigned xcc;
        asm volatile("s_getreg_b32 %0, hwreg(HW_REG_XCC_ID)" : "=s"(xcc));
        int xcd = (int)(xcc & 7);
        int* flags = ctr;
        int* gctr  = ctr + 32;
        int pick = -1;
        #pragma unroll 1
        for (int c = 0; c < 4 && pick < 0; ++c) {
            int ch = xcd*4 + c;
            if (atomicCAS(&flags[ch], 0, 1) == 0) pick = ch;
        }
        if (pick >= 0) {
            atomicAdd(gctr, 1);
        } else {
            long long t0 = clock64();
            #pragma unroll 1
            while (atomicAdd(gctr, 0) < 32 && (clock64() - t0) < 200000) {}
            if (atomicAdd(gctr, 0) < 32) {
                #pragma unroll 1
                for (int ch = 0; ch < 32 && pick < 0; ++ch)
                    if (atomicCAS(&flags[ch], 0, 1) == 0) { pick = ch; atomicAdd(gctr, 1); }
            }
        }
        sh_ec = pick;
    }
    __syncthreads();
    if (sh_ec < 0) return;      // no work for this block
    int chunk = sh_ec;
    int enc = chunk >> 3;
    int b0 = (chunk & 7) * 16;

    const int* toks = (enc < 2) ? iq : ir;
    const int* lens = (enc < 2) ? ql : rl;
    const bool bw = (enc & 1);

    const f16x8* gB1 = gB + (size_t)(enc*2 + 0) * 32768;
    const f16x8* gB2 = gB + (size_t)(enc*2 + 1) * 32768;
    const f16x8* cB1 = cB + (size_t)(enc*2 + 0) * 16384;
    const f16x8* cB2 = cB + (size_t)(enc*2 + 1) * 16384;

    __shared__ __align__(16) unsigned short X0[4096], X1[4096], H0[4096], H1[4096];
    __shared__ float h1s[16*HS], h2s[16*HS], gzs[16*HS];
    __shared__ float gbl[2][512], cbl[2][256];
    __shared__ int tok_s[16], len_s[16];

    for (int i = tid; i < 2048; i += 1024) {
        ((unsigned int*)X0)[i] = 0; ((unsigned int*)X1)[i] = 0;
        ((unsigned int*)H0)[i] = 0; ((unsigned int*)H1)[i] = 0;
    }
    for (int i = tid; i < 16*HS; i += 1024) { h1s[i] = 0.f; h2s[i] = 0.f; }
    if (tid < 512) {
        gbl[0][tid] = gate_b[(enc*2+0)*512 + tid];
        gbl[1][tid] = gate_b[(enc*2+1)*512 + tid];
    }
    if (tid < 256) {
        cbl[0][tid] = cand_b[(enc*2+0)*256 + tid];
        cbl[1][tid] = cand_b[(enc*2+1)*256 + tid];
    }
    if (tid < 16) len_s[tid] = lens[b0 + tid];
    __syncthreads();
    int maxlen = 0;
    #pragma unroll
    for (int r = 0; r < 16; ++r) maxlen = max(maxlen, len_s[r]);
    if (tid < 16) {
        tok_s[tid] = toks[(b0 + tid)*64 + (bw ? (len_s[tid] - 1) : 0)];
    }
    __syncthreads();
    for (int i = tid; i < 2048; i += 1024) {   // fill X0 with x(0), 16 rows
        int row = i >> 7, cp = i & 127;
        float2 xv = *(const float2*)(emb + (size_t)tok_s[row]*256 + 2*cp);
        unsigned int pk = (unsigned int)f16b(xv.x) | ((unsigned int)f16b(xv.y) << 16);
        ((unsigned int*)X0)[(row*256 + ((2*cp) ^ ((row & 7) << 3))) >> 1] = pk;
    }
    __syncthreads();

    for (int t = 0; t < maxlen; ++t) {
        gate_phase(X0, H0, H1, gzs, h1s, gbl[0], gB1, w, l);
        __syncthreads();
        cand_phase<1>(X0, H1, X1, H0, h1s, h2s, gzs, cbl[0], cB1, emb, tok_s, len_s, t, w, l);
        __syncthreads();
        gate_phase(X1, H0, H1, gzs, h2s, gbl[1], gB2, w, l);
        if (tid < 16) {
            int t2 = t + 1;
            if (t2 < 64) {
                int len = len_s[tid];
                int tt = bw ? ((t2 < len) ? (len - 1 - t2) : t2) : t2;
                tok_s[tid] = toks[(b0 + tid)*64 + tt];
            }
        }
        __syncthreads();
        cand_phase<2>(X1, H1, X0, H0, h2s, h1s, gzs, cbl[1], cB2, emb, tok_s, len_s, t, w, l);
        __syncthreads();
    }

    float* outp = (enc < 2) ? Qo : Ro;
    int off = (enc & 1) ? 512 : 0;
    for (int i = tid; i < 4096; i += 1024) {
        int r = i >> 8, c = i & 255;
        outp[(size_t)(b0 + r)*1024 + off + c]       = h1s[r*HS + c];
        outp[(size_t)(b0 + r)*1024 + off + 256 + c] = h2s[r*HS + c];
    }
}

// ---------------- dist / ab (unchanged fp32) --------------------------------------
__global__ void dist_kernel(const float* __restrict__ Q, const float* __restrict__ R,
                            float* __restrict__ dist)
{
    int gidx = blockIdx.x * 256 + threadIdx.x;
    int i = gidx >> 7, j = gidx & 127;
    const float4* q4 = (const float4*)(Q + (size_t)i * 1024);
    const float4* r4 = (const float4*)(R + (size_t)j * 1024);
    float acc = 0.f;
    for (int k = 0; k < 256; ++k) {
        float4 a = q4[k], b = r4[k];
        acc += a.x * b.x + a.y * b.y + a.z * b.z + a.w * b.w;
    }
    dist[gidx] = acc;
}

__global__ __launch_bounds__(256) void ab_kernel(
    const float* __restrict__ Q, const float* __restrict__ R,
    const float* __restrict__ w1, float* __restrict__ A, float* __restrict__ Bv)
{
    int nb = blockIdx.x, rb = blockIdx.y, mat = blockIdx.z;
    int tid = threadIdx.x;
    int n = nb * 256 + tid;
    int r0 = rb * 16;
    const float* src   = mat ? R : Q;
    const float* wmain = mat ? (w1 + (size_t)3073 * 1024) : w1;
    const float* wdiff = w1 + (size_t)1025 * 1024;
    float sgn = mat ? -1.f : 1.f;

    __shared__ float Qs[16][64];
    float acc[16];
    #pragma unroll
    for (int r = 0; r < 16; ++r) acc[r] = 0.f;

    for (int k0 = 0; k0 < 1024; k0 += 64) {
        __syncthreads();
        #pragma unroll
        for (int s = 0; s < 4; ++s) {
            int e = s * 256 + tid;
            int r = e >> 6, kk = e & 63;
            Qs[r][kk] = src[(size_t)(r0 + r) * 1024 + k0 + kk];
        }
        __syncthreads();
        for (int kk = 0; kk < 64; ++kk) {
            size_t row = (size_t)(k0 + kk) * 1024 + n;
            float w = wmain[row] + sgn * wdiff[row];
            #pragma unroll
            for (int r = 0; r < 16; ++r)
                acc[r] = fmaf(Qs[r][kk], w, acc[r]);
        }
    }
    float* dst = mat ? Bv : A;
    #pragma unroll
    for (int r = 0; r < 16; ++r)
        dst[(size_t)(r0 + r) * 1024 + n] = acc[r];
}

// ---------------- pair GEMM: 128x128 tile MFMA, fused epilogue --------------------
__global__ __launch_bounds__(512, 2) void pair_gemm(
    const float* __restrict__ Q, const float* __restrict__ R,
    const float* __restrict__ Aq, const float* __restrict__ Bv,
    const float* __restrict__ dist,
    const int* __restrict__ nqi, const int* __restrict__ nri,
    const f16x8* __restrict__ wB,
    const float* __restrict__ w1, const float* __restrict__ b1,
    const float* __restrict__ w2, float* __restrict__ partial)
{
    int bm = blockIdx.x, bn = blockIdx.y;
    int tid = threadIdx.x, w = tid >> 6, l = tid & 63;
    __shared__ __align__(16) unsigned short As[4096];    // [128 rows][32 k] f16, k-octet ^ (row&3)
    __shared__ float red[2048];                          // [8 waves][128 rows][2]
    __shared__ int qis[128], ris[128];
    __shared__ float dsv[128];
    if (tid < 128) {
        int p = bm*128 + tid;
        int qi = (p < 128) ? p : nqi[p-128];
        int ri = (p < 128) ? p : nri[p-128];
        qis[tid] = qi; ris[tid] = ri; dsv[tid] = dist[qi*128 + ri];
    }
    __syncthreads();

    int srow = tid & 127, skg = tid >> 7;
    const float* qrow = Q + (size_t)qis[srow]*1024 + skg*8;
    const float* rrow = R + (size_t)ris[srow]*1024 + skg*8;

    float4 qa = *(const float4*)(qrow);
    float4 qb = *(const float4*)(qrow + 4);
    float4 ra = *(const float4*)(rrow);
    float4 rb = *(const float4*)(rrow + 4);

    f32x4 acc[8];
    #pragma unroll
    for (int m = 0; m < 8; ++m) acc[m] = (f32x4){0.f,0.f,0.f,0.f};

    for (int kt = 0; kt < 32; ++kt) {
        f16x8 prod;
        prod[0]=(_Float16)(qa.x*ra.x); prod[1]=(_Float16)(qa.y*ra.y);
        prod[2]=(_Float16)(qa.z*ra.z); prod[3]=(_Float16)(qa.w*ra.w);
        prod[4]=(_Float16)(qb.x*rb.x); prod[5]=(_Float16)(qb.y*rb.y);
        prod[6]=(_Float16)(qb.z*rb.z); prod[7]=(_Float16)(qb.w*rb.w);
        __syncthreads();
        ((f16x8*)As)[srow*4 + (skg ^ (srow & 3))] = prod;
        __syncthreads();
        if (kt + 1 < 32) {
            qa = *(const float4*)(qrow + (kt+1)*32);
            qb = *(const float4*)(qrow + (kt+1)*32 + 4);
            ra = *(const float4*)(rrow + (kt+1)*32);
            rb = *(const float4*)(rrow + (kt+1)*32 + 4);
        }
        f16x8 bf = wB[((size_t)kt*64 + bn*8 + w)*64 + l];
        #pragma unroll
        for (int mt = 0; mt < 8; ++mt) {
            f16x8 af = ((const f16x8*)As)[(mt*16 + (l & 15))*4 + ((l >> 4) ^ (l & 3))];
            acc[mt] = MFMA16(af, bf, acc[mt], 0, 0, 0);
        }
    }

    int col = bn*128 + w*16 + (l & 15);
    float wd  = w1[(size_t)1024*1024 + col];
    float b1v = b1[col];
    float w20 = w2[col*2], w21 = w2[col*2 + 1];
    #pragma unroll
    for (int mt = 0; mt < 8; ++mt) {
        float po0[4], po1[4];
        #pragma unroll
        for (int j = 0; j < 4; ++j) {
            int lr = mt*16 + (l >> 4)*4 + j;
            float h = acc[mt][j]
                    + Aq[(size_t)qis[lr]*1024 + col]
                    + Bv[(size_t)ris[lr]*1024 + col]
                    + dsv[lr]*wd + b1v;
            h = fmaxf(h, 0.f);
            po0[j] = h * w20; po1[j] = h * w21;
        }
        #pragma unroll
        for (int s = 1; s < 16; s <<= 1) {
            #pragma unroll
            for (int j = 0; j < 4; ++j) {
                po0[j] += __shfl_xor(po0[j], s, 64);
                po1[j] += __shfl_xor(po1[j], s, 64);
            }
        }
        if ((l & 15) == 0) {
            #pragma unroll
            for (int j = 0; j < 4; ++j) {
                int row = mt*16 + (l >> 4)*4 + j;
                red[(w*128 + row)*2 + 0] = po0[j];
                red[(w*128 + row)*2 + 1] = po1[j];
            }
        }
    }
    __syncthreads();
    if (tid < 256) {
        int row = tid >> 1, cc = tid & 1;
        float s = 0.f;
        #pragma unroll
        for (int ww = 0; ww < 8; ++ww) s += red[(ww*128 + row)*2 + cc];
        partial[((size_t)bn*16384 + bm*128 + row)*2 + cc] = s;
    }
}

__global__ void final_reduce(const float* __restrict__ partial,
                             const float* __restrict__ b2, float* __restrict__ out)
{
    int gidx = blockIdx.x * 256 + threadIdx.x;
    int p = gidx >> 1, c = gidx & 1;
    float s = b2[c];
    #pragma unroll
    for (int nt = 0; nt < 8; ++nt)
        s += partial[((size_t)nt * 16384 + p) * 2 + c];
    out[gidx] = s;
}

extern "C" void kernel_launch(void* const* d_in, const int* in_sizes, int n_in,
                              void* d_out, int out_size, void* d_ws, size_t ws_size,
                              hipStream_t stream) {
    const int*   iq     = (const int*)d_in[0];
    const int*   ir     = (const int*)d_in[1];
    const int*   ql     = (const int*)d_in[2];
    const int*   rl     = (const int*)d_in[3];
    const int*   nqi    = (const int*)d_in[4];
    const int*   nri    = (const int*)d_in[5];
    const float* emb    = (const float*)d_in[6];
    const float* gate_k = (const float*)d_in[7];
    const float* gate_b = (const float*)d_in[8];
    const float* cand_k = (const float*)d_in[9];
    const float* cand_b = (const float*)d_in[10];
    const float* w1     = (const float*)d_in[11];
    const float* b1     = (const float*)d_in[12];
    const float* w2     = (const float*)d_in[13];
    const float* b2     = (const float*)d_in[14];
    float* out = (float*)d_out;
    float* ws  = (float*)d_ws;

    float* Q       = ws;                  // 131072
    float* R       = ws + 131072;         // 131072
    float* A       = ws + 262144;         // 131072
    float* Bv      = ws + 393216;         // 131072
    float* dist    = ws + 524288;         // 16384
    float* partial = ws + 540672;         // 8*16384*2 = 262144
    f16x8* gB      = (f16x8*)(ws + 802816);   // 262144 frags
    f16x8* cB      = (f16x8*)(ws + 1851392);  // 131072 frags
    f16x8* wB      = (f16x8*)(ws + 2375680);  // 131072 frags
    int*   ctr     = (int*)(ws + 2899968);    // 32 chunk flags + gctr

    conv_gru<<<1024, 256, 0, stream>>>(gate_k, cand_k, gB, cB, ctr);
    conv_wprod<<<512, 256, 0, stream>>>(w1, wB);
    gru_encode<<<256, 1024, 0, stream>>>(iq, ir, ql, rl, emb, gate_b, cand_b,
                                         gB, cB, ctr, Q, R);
    dist_kernel<<<64, 256, 0, stream>>>(Q, R, dist);
    ab_kernel<<<dim3(4, 8, 2), 256, 0, stream>>>(Q, R, w1, A, Bv);
    pair_gemm<<<dim3(128, 8), 512, 0, stream>>>(Q, R, A, Bv, dist, nqi, nri,
                                                wB, w1, b1, w2, partial);
    final_reduce<<<128, 256, 0, stream>>>(partial, b2, out);
}

// Round 12
// 1722.072 us; speedup vs baseline: 2.1113x; 2.1113x over previous
//
#include <hip/hip_runtime.h>
#include <hip/hip_fp16.h>
#include <cmath>

typedef _Float16 h2 __attribute__((ext_vector_type(2)));
typedef _Float16 f16x8 __attribute__((ext_vector_type(8)));
typedef float f32x4 __attribute__((ext_vector_type(4)));

#define MFMA16 __builtin_amdgcn_mfma_f32_16x16x32_f16

#if defined(__has_builtin)
#if __has_builtin(__builtin_amdgcn_fdot2)
#define HAS_FDOT2 1
#endif
#endif

__device__ __forceinline__ float fdot2f(h2 a, h2 b, float c) {
#ifdef HAS_FDOT2
    return __builtin_amdgcn_fdot2(a, b, c, false);
#else
    c = fmaf((float)a[0], (float)b[0], c);
    return fmaf((float)a[1], (float)b[1], c);
#endif
}

__device__ __forceinline__ float sigm(float x) { return 1.0f / (1.0f + expf(-x)); }
__device__ __forceinline__ unsigned short f16b(float x) {
    _Float16 h = (_Float16)x; return __builtin_bit_cast(unsigned short, h);
}

// ---- weight conversion: fp32 -> k-pair-packed f16 (round-4 proven) --------------
// gkh[e2][kp][col] = h2(gk[e2][2kp][col], gk[e2][2kp+1][col])   col in [0,512)
// ckh[e2][kp][col] = h2(ck[e2][2kp][col], ck[e2][2kp+1][col])   col in [0,256)
__global__ __launch_bounds__(256) void convert_weights(
    const float* __restrict__ gate_k, const float* __restrict__ cand_k,
    float* __restrict__ gkh, float* __restrict__ ckh)
{
    int i = blockIdx.x * 256 + threadIdx.x;
    if (i < 8 * 256 * 512) {
        int col = i & 511, kp = (i >> 9) & 255, e2 = i >> 17;
        const float* src = gate_k + ((size_t)e2 * 512 + 2 * kp) * 512 + col;
        h2 v; v[0] = (_Float16)src[0]; v[1] = (_Float16)src[512];
        gkh[i] = __builtin_bit_cast(float, v);
    }
    if (i < 8 * 256 * 256) {
        int col = i & 255, kp = (i >> 8) & 255, e2 = i >> 16;
        const float* src = cand_k + ((size_t)e2 * 512 + 2 * kp) * 256 + col;
        h2 v; v[0] = (_Float16)src[0]; v[1] = (_Float16)src[256];
        ckh[i] = __builtin_bit_cast(float, v);
    }
}

// ---- Wprod pack into per-lane MFMA B-fragment layout (for pair_gemm) ------------
__global__ __launch_bounds__(256) void conv_wprod(const float* __restrict__ w1,
                                                  f16x8* __restrict__ wB)
{
    int i = blockIdx.x * 256 + threadIdx.x;   // [kt 32][nt 64][l 64]
    int l = i & 63, nt = (i >> 6) & 63, kt = i >> 12;
    int k0 = kt*32 + ((l >> 4) << 3);
    int n  = (nt << 4) + (l & 15);
    const float* src = w1 + (size_t)(2049 + k0) * 1024 + n;
    f16x8 v;
    #pragma unroll
    for (int j = 0; j < 8; ++j) v[j] = (_Float16)src[(size_t)j * 1024];
    wB[i] = v;
}

// ---- GRU hot loops (f16 dot2, round-4 proven: L2-resident weight stream) --------
// in0f layout: f16 element (k, row) at  (k>>1)*8 + row*2 + (k&1)
__device__ __forceinline__ void gate_partial_h(
    const _Float16* in0f, float* pbuf, const float* __restrict__ gk, int tid)
{
    int cg = tid & 127, q = tid >> 7;
    int c0 = cg * 4;
    const float* gp = gk + (size_t)(q * 32) * 512 + c0;
    const _Float16* xp = in0f + q * 32 * 8;
    float4 A0 = {0.f,0.f,0.f,0.f}, A1 = {0.f,0.f,0.f,0.f};
    float4 A2 = {0.f,0.f,0.f,0.f}, A3 = {0.f,0.f,0.f,0.f};
    #pragma unroll 8
    for (int i = 0; i < 32; ++i) {
        float4 wf = *(const float4*)(gp + (size_t)i * 512);
        float4 xf = *(const float4*)(xp + i * 8);
        h2 w0 = __builtin_bit_cast(h2, wf.x), w1 = __builtin_bit_cast(h2, wf.y);
        h2 w2 = __builtin_bit_cast(h2, wf.z), w3 = __builtin_bit_cast(h2, wf.w);
        h2 x0 = __builtin_bit_cast(h2, xf.x), x1 = __builtin_bit_cast(h2, xf.y);
        h2 x2 = __builtin_bit_cast(h2, xf.z), x3 = __builtin_bit_cast(h2, xf.w);
        A0.x = fdot2f(x0, w0, A0.x); A0.y = fdot2f(x0, w1, A0.y);
        A0.z = fdot2f(x0, w2, A0.z); A0.w = fdot2f(x0, w3, A0.w);
        A1.x = fdot2f(x1, w0, A1.x); A1.y = fdot2f(x1, w1, A1.y);
        A1.z = fdot2f(x1, w2, A1.z); A1.w = fdot2f(x1, w3, A1.w);
        A2.x = fdot2f(x2, w0, A2.x); A2.y = fdot2f(x2, w1, A2.y);
        A2.z = fdot2f(x2, w2, A2.z); A2.w = fdot2f(x2, w3, A2.w);
        A3.x = fdot2f(x3, w0, A3.x); A3.y = fdot2f(x3, w1, A3.y);
        A3.z = fdot2f(x3, w2, A3.z); A3.w = fdot2f(x3, w3, A3.w);
    }
    *(float4*)&pbuf[(q * 4 + 0) * 512 + c0] = A0;
    *(float4*)&pbuf[(q * 4 + 1) * 512 + c0] = A1;
    *(float4*)&pbuf[(q * 4 + 2) * 512 + c0] = A2;
    *(float4*)&pbuf[(q * 4 + 3) * 512 + c0] = A3;
}

__device__ __forceinline__ void cand_partial_h(
    const _Float16* in0f, float* pbuf, const float* __restrict__ ck, int tid)
{
    int cg = tid & 63, q = tid >> 6;
    int c0 = cg * 4;
    const float* cp = ck + (size_t)(q * 16) * 256 + c0;
    const _Float16* xp = in0f + q * 16 * 8;
    float4 A0 = {0.f,0.f,0.f,0.f}, A1 = {0.f,0.f,0.f,0.f};
    float4 A2 = {0.f,0.f,0.f,0.f}, A3 = {0.f,0.f,0.f,0.f};
    #pragma unroll 8
    for (int i = 0; i < 16; ++i) {
        float4 wf = *(const float4*)(cp + (size_t)i * 256);
        float4 xf = *(const float4*)(xp + i * 8);
        h2 w0 = __builtin_bit_cast(h2, wf.x), w1 = __builtin_bit_cast(h2, wf.y);
        h2 w2 = __builtin_bit_cast(h2, wf.z), w3 = __builtin_bit_cast(h2, wf.w);
        h2 x0 = __builtin_bit_cast(h2, xf.x), x1 = __builtin_bit_cast(h2, xf.y);
        h2 x2 = __builtin_bit_cast(h2, xf.z), x3 = __builtin_bit_cast(h2, xf.w);
        A0.x = fdot2f(x0, w0, A0.x); A0.y = fdot2f(x0, w1, A0.y);
        A0.z = fdot2f(x0, w2, A0.z); A0.w = fdot2f(x0, w3, A0.w);
        A1.x = fdot2f(x1, w0, A1.x); A1.y = fdot2f(x1, w1, A1.y);
        A1.z = fdot2f(x1, w2, A1.z); A1.w = fdot2f(x1, w3, A1.w);
        A2.x = fdot2f(x2, w0, A2.x); A2.y = fdot2f(x2, w1, A2.y);
        A2.z = fdot2f(x2, w2, A2.z); A2.w = fdot2f(x2, w3, A2.w);
        A3.x = fdot2f(x3, w0, A3.x); A3.y = fdot2f(x3, w1, A3.y);
        A3.z = fdot2f(x3, w2, A3.z); A3.w = fdot2f(x3, w3, A3.w);
    }
    *(float4*)&pbuf[(q * 4 + 0) * 256 + c0] = A0;
    *(float4*)&pbuf[(q * 4 + 1) * 256 + c0] = A1;
    *(float4*)&pbuf[(q * 4 + 2) * 256 + c0] = A2;
    *(float4*)&pbuf[(q * 4 + 3) * 256 + c0] = A3;
}

// grid = 128 blocks x 1024 threads; block = (encoder, 4-row chunk), fully
// workgroup-local recurrence; f16 weights, fp32 h state/partials. (round-4 exact)
__global__ __launch_bounds__(1024, 4) void gru_encode(
    const int* __restrict__ iq, const int* __restrict__ ir,
    const int* __restrict__ ql, const int* __restrict__ rl,
    const float* __restrict__ emb,
    const float* __restrict__ gkh, const float* __restrict__ gate_b,
    const float* __restrict__ ckh, const float* __restrict__ cand_b,
    float* __restrict__ Qo, float* __restrict__ Ro)
{
    int bid = blockIdx.x;
    int xcd = bid & 7;
    int enc = xcd >> 1;
    int chunk = (xcd & 1) * 16 + (bid >> 3);
    int b0 = chunk * 4;
    int tid = threadIdx.x;
    int c = tid & 255, r = tid >> 8;

    const int* toks = (enc < 2) ? iq : ir;
    const int* lens = (enc < 2) ? ql : rl;
    const bool bw = (enc & 1);

    const float* gk1 = gkh + (size_t)(enc * 2 + 0) * 131072;
    const float* gk2 = gkh + (size_t)(enc * 2 + 1) * 131072;
    const float* gb1 = gate_b + (enc * 2 + 0) * 512;
    const float* gb2 = gate_b + (enc * 2 + 1) * 512;
    const float* ck1 = ckh + (size_t)(enc * 2 + 0) * 65536;
    const float* ck2 = ckh + (size_t)(enc * 2 + 1) * 65536;
    const float* cb1 = cand_b + (enc * 2 + 0) * 256;
    const float* cb2 = cand_b + (enc * 2 + 1) * 256;

    __shared__ __align__(16) _Float16 in0f[256 * 8];   // 4KB  [kp][row*2+(k&1)]
    __shared__ float pbuf[16384];                      // 64KB partials
    __shared__ float h1rt[4][256];
    __shared__ float h2rt[4][256];
    __shared__ float gzt[4][256];
    __shared__ int tok_s[4];
    __shared__ int len_s[4];

    h1rt[r][c] = 0.f;
    h2rt[r][c] = 0.f;
    if (tid < 4) len_s[tid] = lens[b0 + tid];
    __syncthreads();
    int maxlen = max(max(len_s[0], len_s[1]), max(len_s[2], len_s[3]));
    if (tid < 4) {
        int len = len_s[tid];
        tok_s[tid] = toks[(b0 + tid) * 64 + (bw ? (len - 1) : 0)];
    }
    __syncthreads();

    for (int t = 0; t < maxlen; ++t) {
        // FILL: in0f = [x_t ; h1] as f16 pairs (pair-per-thread, b32 writes)
        if (tid < 512) {
            int kp = tid >> 2, rr = tid & 3;
            float2 xv = *(const float2*)(emb + (size_t)tok_s[rr] * 256 + 2 * kp);
            h2 v; v[0] = (_Float16)xv.x; v[1] = (_Float16)xv.y;
            *(float*)(in0f + kp * 8 + rr * 2) = __builtin_bit_cast(float, v);
        } else {
            int m = (tid - 512) >> 2, rr = tid & 3;
            h2 v; v[0] = (_Float16)h1rt[rr][2 * m]; v[1] = (_Float16)h1rt[rr][2 * m + 1];
            *(float*)(in0f + (128 + m) * 8 + rr * 2) = __builtin_bit_cast(float, v);
        }
        __syncthreads();

        // ---- layer 1 ----
        gate_partial_h(in0f, pbuf, gk1, tid);
        __syncthreads();
        {
            float s0 = gb1[c], s1 = gb1[256 + c];
            #pragma unroll
            for (int q = 0; q < 8; ++q) {
                s0 += pbuf[(q * 4 + r) * 512 + c];
                s1 += pbuf[(q * 4 + r) * 512 + c + 256];
            }
            float rh = sigm(s0) * h1rt[r][c];
            gzt[r][c] = sigm(s1);
            in0f[((256 + c) >> 1) * 8 + r * 2 + (c & 1)] = (_Float16)rh;
        }
        __syncthreads();
        cand_partial_h(in0f, pbuf, ck1, tid);
        __syncthreads();
        {
            float s = cb1[c];
            #pragma unroll
            for (int q = 0; q < 16; ++q) s += pbuf[(q * 4 + r) * 256 + c];
            float cv = tanhf(s);
            float z = gzt[r][c];
            float hn = fmaf(z, h1rt[r][c] - cv, cv);
            if (t < len_s[r]) h1rt[r][c] = hn;
            in0f[(c >> 1) * 8 + r * 2 + (c & 1)]         = (_Float16)hn;
            in0f[((256 + c) >> 1) * 8 + r * 2 + (c & 1)] = (_Float16)h2rt[r][c];
        }
        __syncthreads();

        // ---- layer 2 ----
        gate_partial_h(in0f, pbuf, gk2, tid);
        __syncthreads();
        {
            float s0 = gb2[c], s1 = gb2[256 + c];
            #pragma unroll
            for (int q = 0; q < 8; ++q) {
                s0 += pbuf[(q * 4 + r) * 512 + c];
                s1 += pbuf[(q * 4 + r) * 512 + c + 256];
            }
            float rh = sigm(s0) * h2rt[r][c];
            gzt[r][c] = sigm(s1);
            in0f[((256 + c) >> 1) * 8 + r * 2 + (c & 1)] = (_Float16)rh;
        }
        __syncthreads();
        cand_partial_h(in0f, pbuf, ck2, tid);
        __syncthreads();
        {
            float s = cb2[c];
            #pragma unroll
            for (int q = 0; q < 16; ++q) s += pbuf[(q * 4 + r) * 256 + c];
            float cv = tanhf(s);
            float z = gzt[r][c];
            float hn = fmaf(z, h2rt[r][c] - cv, cv);
            if (t < len_s[r]) h2rt[r][c] = hn;
        }
        if (tid < 4) {   // token prefetch for t+1
            int t2 = t + 1;
            if (t2 < 64) {
                int len = len_s[tid];
                int tt = bw ? ((t2 < len) ? (len - 1 - t2) : t2) : t2;
                tok_s[tid] = toks[(b0 + tid) * 64 + tt];
            }
        }
        __syncthreads();
    }

    float* outp = (enc < 2) ? Qo : Ro;
    int off = (enc & 1) ? 512 : 0;
    outp[(size_t)(b0 + r) * 1024 + off + c]       = h1rt[r][c];
    outp[(size_t)(b0 + r) * 1024 + off + 256 + c] = h2rt[r][c];
}

// ---------------- dist / ab (unchanged fp32) --------------------------------------
__global__ void dist_kernel(const float* __restrict__ Q, const float* __restrict__ R,
                            float* __restrict__ dist)
{
    int gidx = blockIdx.x * 256 + threadIdx.x;
    int i = gidx >> 7, j = gidx & 127;
    const float4* q4 = (const float4*)(Q + (size_t)i * 1024);
    const float4* r4 = (const float4*)(R + (size_t)j * 1024);
    float acc = 0.f;
    for (int k = 0; k < 256; ++k) {
        float4 a = q4[k], b = r4[k];
        acc += a.x * b.x + a.y * b.y + a.z * b.z + a.w * b.w;
    }
    dist[gidx] = acc;
}

__global__ __launch_bounds__(256) void ab_kernel(
    const float* __restrict__ Q, const float* __restrict__ R,
    const float* __restrict__ w1, float* __restrict__ A, float* __restrict__ Bv)
{
    int nb = blockIdx.x, rb = blockIdx.y, mat = blockIdx.z;
    int tid = threadIdx.x;
    int n = nb * 256 + tid;
    int r0 = rb * 16;
    const float* src   = mat ? R : Q;
    const float* wmain = mat ? (w1 + (size_t)3073 * 1024) : w1;
    const float* wdiff = w1 + (size_t)1025 * 1024;
    float sgn = mat ? -1.f : 1.f;

    __shared__ float Qs[16][64];
    float acc[16];
    #pragma unroll
    for (int r = 0; r < 16; ++r) acc[r] = 0.f;

    for (int k0 = 0; k0 < 1024; k0 += 64) {
        __syncthreads();
        #pragma unroll
        for (int s = 0; s < 4; ++s) {
            int e = s * 256 + tid;
            int r = e >> 6, kk = e & 63;
            Qs[r][kk] = src[(size_t)(r0 + r) * 1024 + k0 + kk];
        }
        __syncthreads();
        for (int kk = 0; kk < 64; ++kk) {
            size_t row = (size_t)(k0 + kk) * 1024 + n;
            float w = wmain[row] + sgn * wdiff[row];
            #pragma unroll
            for (int r = 0; r < 16; ++r)
                acc[r] = fmaf(Qs[r][kk], w, acc[r]);
        }
    }
    float* dst = mat ? Bv : A;
    #pragma unroll
    for (int r = 0; r < 16; ++r)
        dst[(size_t)(r0 + r) * 1024 + n] = acc[r];
}

// ---------------- pair GEMM: 128x128 tile MFMA, fused epilogue --------------------
__global__ __launch_bounds__(512, 2) void pair_gemm(
    const float* __restrict__ Q, const float* __restrict__ R,
    const float* __restrict__ Aq, const float* __restrict__ Bv,
    const float* __restrict__ dist,
    const int* __restrict__ nqi, const int* __restrict__ nri,
    const f16x8* __restrict__ wB,
    const float* __restrict__ w1, const float* __restrict__ b1,
    const float* __restrict__ w2, float* __restrict__ partial)
{
    int bm = blockIdx.x, bn = blockIdx.y;
    int tid = threadIdx.x, w = tid >> 6, l = tid & 63;
    __shared__ __align__(16) unsigned short As[4096];    // [128 rows][32 k] f16, k-octet ^ (row&3)
    __shared__ float red[2048];                          // [8 waves][128 rows][2]
    __shared__ int qis[128], ris[128];
    __shared__ float dsv[128];
    if (tid < 128) {
        int p = bm*128 + tid;
        int qi = (p < 128) ? p : nqi[p-128];
        int ri = (p < 128) ? p : nri[p-128];
        qis[tid] = qi; ris[tid] = ri; dsv[tid] = dist[qi*128 + ri];
    }
    __syncthreads();

    int srow = tid & 127, skg = tid >> 7;
    const float* qrow = Q + (size_t)qis[srow]*1024 + skg*8;
    const float* rrow = R + (size_t)ris[srow]*1024 + skg*8;

    float4 qa = *(const float4*)(qrow);
    float4 qb = *(const float4*)(qrow + 4);
    float4 ra = *(const float4*)(rrow);
    float4 rb = *(const float4*)(rrow + 4);

    f32x4 acc[8];
    #pragma unroll
    for (int m = 0; m < 8; ++m) acc[m] = (f32x4){0.f,0.f,0.f,0.f};

    for (int kt = 0; kt < 32; ++kt) {
        f16x8 prod;
        prod[0]=(_Float16)(qa.x*ra.x); prod[1]=(_Float16)(qa.y*ra.y);
        prod[2]=(_Float16)(qa.z*ra.z); prod[3]=(_Float16)(qa.w*ra.w);
        prod[4]=(_Float16)(qb.x*rb.x); prod[5]=(_Float16)(qb.y*rb.y);
        prod[6]=(_Float16)(qb.z*rb.z); prod[7]=(_Float16)(qb.w*rb.w);
        __syncthreads();
        ((f16x8*)As)[srow*4 + (skg ^ (srow & 3))] = prod;
        __syncthreads();
        if (kt + 1 < 32) {
            qa = *(const float4*)(qrow + (kt+1)*32);
            qb = *(const float4*)(qrow + (kt+1)*32 + 4);
            ra = *(const float4*)(rrow + (kt+1)*32);
            rb = *(const float4*)(rrow + (kt+1)*32 + 4);
        }
        f16x8 bf = wB[((size_t)kt*64 + bn*8 + w)*64 + l];
        #pragma unroll
        for (int mt = 0; mt < 8; ++mt) {
            f16x8 af = ((const f16x8*)As)[(mt*16 + (l & 15))*4 + ((l >> 4) ^ (l & 3))];
            acc[mt] = MFMA16(af, bf, acc[mt], 0, 0, 0);
        }
    }

    int col = bn*128 + w*16 + (l & 15);
    float wd  = w1[(size_t)1024*1024 + col];
    float b1v = b1[col];
    float w20 = w2[col*2], w21 = w2[col*2 + 1];
    #pragma unroll
    for (int mt = 0; mt < 8; ++mt) {
        float po0[4], po1[4];
        #pragma unroll
        for (int j = 0; j < 4; ++j) {
            int lr = mt*16 + (l >> 4)*4 + j;
            float h = acc[mt][j]
                    + Aq[(size_t)qis[lr]*1024 + col]
                    + Bv[(size_t)ris[lr]*1024 + col]
                    + dsv[lr]*wd + b1v;
            h = fmaxf(h, 0.f);
            po0[j] = h * w20; po1[j] = h * w21;
        }
        #pragma unroll
        for (int s = 1; s < 16; s <<= 1) {
            #pragma unroll
            for (int j = 0; j < 4; ++j) {
                po0[j] += __shfl_xor(po0[j], s, 64);
                po1[j] += __shfl_xor(po1[j], s, 64);
            }
        }
        if ((l & 15) == 0) {
            #pragma unroll
            for (int j = 0; j < 4; ++j) {
                int row = mt*16 + (l >> 4)*4 + j;
                red[(w*128 + row)*2 + 0] = po0[j];
                red[(w*128 + row)*2 + 1] = po1[j];
            }
        }
    }
    __syncthreads();
    if (tid < 256) {
        int row = tid >> 1, cc = tid & 1;
        float s = 0.f;
        #pragma unroll
        for (int ww = 0; ww < 8; ++ww) s += red[(ww*128 + row)*2 + cc];
        partial[((size_t)bn*16384 + bm*128 + row)*2 + cc] = s;
    }
}

__global__ void final_reduce(const float* __restrict__ partial,
                             const float* __restrict__ b2, float* __restrict__ out)
{
    int gidx = blockIdx.x * 256 + threadIdx.x;
    int p = gidx >> 1, c = gidx & 1;
    float s = b2[c];
    #pragma unroll
    for (int nt = 0; nt < 8; ++nt)
        s += partial[((size_t)nt * 16384 + p) * 2 + c];
    out[gidx] = s;
}

extern "C" void kernel_launch(void* const* d_in, const int* in_sizes, int n_in,
                              void* d_out, int out_size, void* d_ws, size_t ws_size,
                              hipStream_t stream) {
    const int*   iq     = (const int*)d_in[0];
    const int*   ir     = (const int*)d_in[1];
    const int*   ql     = (const int*)d_in[2];
    const int*   rl     = (const int*)d_in[3];
    const int*   nqi    = (const int*)d_in[4];
    const int*   nri    = (const int*)d_in[5];
    const float* emb    = (const float*)d_in[6];
    const float* gate_k = (const float*)d_in[7];
    const float* gate_b = (const float*)d_in[8];
    const float* cand_k = (const float*)d_in[9];
    const float* cand_b = (const float*)d_in[10];
    const float* w1     = (const float*)d_in[11];
    const float* b1     = (const float*)d_in[12];
    const float* w2     = (const float*)d_in[13];
    const float* b2     = (const float*)d_in[14];
    float* out = (float*)d_out;
    float* ws  = (float*)d_ws;

    float* Q       = ws;                  // 131072
    float* R       = ws + 131072;         // 131072
    float* A       = ws + 262144;         // 131072
    float* Bv      = ws + 393216;         // 131072
    float* dist    = ws + 524288;         // 16384
    float* partial = ws + 540672;         // 8*16384*2 = 262144 (ends 802816)
    float* gkh     = ws + 1064960;        // 8*256*512 floats (h2-packed)
    float* ckh     = ws + 2113536;        // 8*256*256 floats
    f16x8* wB      = (f16x8*)(ws + 2637824);  // 131072 frags = 524288 floats (ends 3162112)

    convert_weights<<<4096, 256, 0, stream>>>(gate_k, cand_k, gkh, ckh);
    conv_wprod<<<512, 256, 0, stream>>>(w1, wB);
    gru_encode<<<128, 1024, 0, stream>>>(iq, ir, ql, rl, emb, gkh, gate_b,
                                         ckh, cand_b, Q, R);
    dist_kernel<<<64, 256, 0, stream>>>(Q, R, dist);
    ab_kernel<<<dim3(4, 8, 2), 256, 0, stream>>>(Q, R, w1, A, Bv);
    pair_gemm<<<dim3(128, 8), 512, 0, stream>>>(Q, R, A, Bv, dist, nqi, nri,
                                                wB, w1, b1, w2, partial);
    final_reduce<<<128, 256, 0, stream>>>(partial, b2, out);
}